// Round 4
// baseline (188.067 us; speedup 1.0000x reference)
//
#include <hip/hip_runtime.h>
#include <hip/hip_bf16.h>
#include <cstdint>

#define B_  2
#define S_  2048
#define D_  1024
#define H_  16
#define HD_ 64
#define M_  (B_ * S_)   // 4096
static constexpr float SC_LOG2E = 0.125f * 1.44269504088896f;  // SCALE * log2(e), folded into Q

typedef __bf16 bf16x8 __attribute__((ext_vector_type(8)));
typedef __bf16 bf16x4 __attribute__((ext_vector_type(4)));
typedef float  f32x4  __attribute__((ext_vector_type(4)));
typedef float  f32x16 __attribute__((ext_vector_type(16)));
typedef unsigned u32x2 __attribute__((ext_vector_type(2)));

__device__ __forceinline__ unsigned short f2b(float f) {
  union { float f; unsigned u; } x; x.f = f;
  unsigned r = x.u + 0x7FFF + ((x.u >> 16) & 1);   // RNE
  return (unsigned short)(r >> 16);
}

__device__ __forceinline__ unsigned cvtpk(float lo, float hi) {   // bf16(lo) | bf16(hi)<<16
  unsigned r;
  asm("v_cvt_pk_bf16_f32 %0, %1, %2" : "=v"(r) : "v"(lo), "v"(hi));
  return r;
}
__device__ __forceinline__ u32x2 pswap(unsigned a, unsigned b) {  // {a.lo|b.lo, a.hi|b.hi} halves
  return __builtin_amdgcn_permlane32_swap(a, b, false, false);
}

// async global->LDS, 16B per lane; HW uses wave-uniform LDS base + lane*16
__device__ __forceinline__ void gl_lds16(const unsigned short* g, unsigned short* l) {
  __builtin_amdgcn_global_load_lds((const __attribute__((address_space(1))) void*)g,
                                   (__attribute__((address_space(3))) void*)l, 16, 0, 0);
}

// Barriers that do NOT drain vmcnt(0) (unlike __syncthreads) — keep global loads in flight.
__device__ __forceinline__ void bar_lgkm() {
  asm volatile("s_waitcnt lgkmcnt(0)\n\ts_barrier" ::: "memory");
}
__device__ __forceinline__ void bar_vm2() {
  asm volatile("s_waitcnt vmcnt(2) lgkmcnt(0)\n\ts_barrier" ::: "memory");
}
__device__ __forceinline__ void bar_vm0() {
  asm volatile("s_waitcnt vmcnt(0) lgkmcnt(0)\n\ts_barrier" ::: "memory");
}

// ------------------------------------------- fused cvt: z<4 -> transpose+cvt W, z==4 -> cvt x
__global__ void cvt_all_kernel(const float* __restrict__ x,
                               const float* __restrict__ w0, const float* __restrict__ w1,
                               const float* __restrict__ w2, const float* __restrict__ w3,
                               unsigned short* __restrict__ xb,
                               unsigned short* __restrict__ o0, unsigned short* __restrict__ o1,
                               unsigned short* __restrict__ o2, unsigned short* __restrict__ o3) {
  int tx = threadIdx.x, ty = threadIdx.y;
  if (blockIdx.z == 4) {
    int tid = ty * 32 + tx;
    int base = ((int)blockIdx.y * 32 + (int)blockIdx.x) * 1024 + tid;  // f4 index
    const float4* xf = (const float4*)x;
    ushort4* ob = (ushort4*)xb;
#pragma unroll
    for (int j = 0; j < 4; j++) {
      float4 v = xf[base + j * 256];
      ushort4 r;
      r.x = f2b(v.x); r.y = f2b(v.y); r.z = f2b(v.z); r.w = f2b(v.w);
      ob[base + j * 256] = r;
    }
    return;
  }
  const float* w = blockIdx.z == 0 ? w0 : blockIdx.z == 1 ? w1 : blockIdx.z == 2 ? w2 : w3;
  unsigned short* o = blockIdx.z == 0 ? o0 : blockIdx.z == 1 ? o1 : blockIdx.z == 2 ? o2 : o3;
  __shared__ float t[32][33];
  int x0 = blockIdx.x * 32, y0 = blockIdx.y * 32;
#pragma unroll
  for (int j = 0; j < 4; j++)
    t[ty + j * 8][tx] = w[(size_t)(y0 + ty + j * 8) * D_ + x0 + tx];
  __syncthreads();
#pragma unroll
  for (int j = 0; j < 4; j++)
    o[(size_t)(x0 + ty + j * 8) * D_ + y0 + tx] = f2b(t[tx][ty + j * 8]);
}

// ---------------------------------------------------------------- QKV GEMM (unchanged)
__global__ __launch_bounds__(512) void qkv_gemm_kernel(
    const unsigned short* __restrict__ xb,
    const unsigned short* __restrict__ wqt, const unsigned short* __restrict__ wkt,
    const unsigned short* __restrict__ wvt,
    const float* __restrict__ bq, const float* __restrict__ bk, const float* __restrict__ bv,
    unsigned short* __restrict__ qo, unsigned short* __restrict__ ko, unsigned short* __restrict__ vo) {
  const unsigned short* wt = blockIdx.z == 0 ? wqt : blockIdx.z == 1 ? wkt : wvt;
  const float* bias        = blockIdx.z == 0 ? bq  : blockIdx.z == 1 ? bk  : bv;
  unsigned short* out      = blockIdx.z == 0 ? qo  : blockIdx.z == 1 ? ko  : vo;
  const float scl = blockIdx.z == 0 ? SC_LOG2E : 1.0f;

  __shared__ __align__(16) unsigned short smem[6 * 4096];   // 48 KB
  const int tid = threadIdx.x;
  const int lane = tid & 63, wid = tid >> 6;
  const int wm = wid & 1, wn = wid >> 1;
  const int m0 = blockIdx.x * 128, n0 = blockIdx.y * 128;
  const int l15 = lane & 15, q4 = lane >> 4;
  const int srow = tid >> 2, skc = (tid & 3) * 8;

  f32x4 zero = {0.f, 0.f, 0.f, 0.f};
  f32x4 acc[4][2];
#pragma unroll
  for (int mt = 0; mt < 4; mt++)
#pragma unroll
    for (int nt = 0; nt < 2; nt++) acc[mt][nt] = zero;

  const unsigned short* ap = xb + (size_t)(m0 + srow) * D_ + skc;
  const unsigned short* bp = wt + (size_t)(n0 + srow) * D_ + skc;
  gl_lds16(ap,      smem + tid * 8);
  gl_lds16(bp,      smem + 12288 + tid * 8);
  gl_lds16(ap + 32, smem + 4096 + tid * 8);
  gl_lds16(bp + 32, smem + 12288 + 4096 + tid * 8);

  int bc = 0;
  for (int it = 0; it < 32; it++) {
    if (it < 31) bar_vm2(); else bar_vm0();
    if (it + 2 < 32) {
      int bn_ = bc < 1 ? bc + 2 : bc - 1;
      gl_lds16(ap + (it + 2) * 32, smem + bn_ * 4096 + tid * 8);
      gl_lds16(bp + (it + 2) * 32, smem + 12288 + bn_ * 4096 + tid * 8);
    }
    const unsigned short* Ab = smem + bc * 4096;
    const unsigned short* Bb = smem + 12288 + bc * 4096;
    bf16x8 af[4], bfv[2];
#pragma unroll
    for (int mt = 0; mt < 4; mt++) af[mt]  = *(const bf16x8*)(Ab + (wm * 64 + mt * 16 + l15) * 32 + q4 * 8);
#pragma unroll
    for (int nt = 0; nt < 2; nt++) bfv[nt] = *(const bf16x8*)(Bb + (wn * 32 + nt * 16 + l15) * 32 + q4 * 8);
#pragma unroll
    for (int mt = 0; mt < 4; mt++)
#pragma unroll
      for (int nt = 0; nt < 2; nt++)
        acc[mt][nt] = __builtin_amdgcn_mfma_f32_16x16x32_bf16(af[mt], bfv[nt], acc[mt][nt], 0, 0, 0);
    bc = bc == 2 ? 0 : bc + 1;
  }

  if (blockIdx.z < 2) {
#pragma unroll
    for (int nt = 0; nt < 2; nt++) {
      int n = n0 + wn * 32 + nt * 16 + l15;
      float bn = bias[n];
      int h = n >> 6, hd = n & 63;
#pragma unroll
      for (int mt = 0; mt < 4; mt++) {
#pragma unroll
        for (int r = 0; r < 4; r++) {
          int m = m0 + wm * 64 + mt * 16 + q4 * 4 + r;
          int b = m >> 11, s = m & (S_ - 1);
          out[(((size_t)(b * H_ + h)) * S_ + s) * HD_ + hd] = f2b((acc[mt][nt][r] + bn) * scl);
        }
      }
    }
  } else {
    unsigned short* buf = smem;
#pragma unroll
    for (int p = 0; p < 2; p++) {
      __syncthreads();
      if ((wn >> 1) == p) {
#pragma unroll
        for (int nt = 0; nt < 2; nt++) {
          int np = (wn & 1) * 32 + nt * 16 + l15;
          float bn = bias[n0 + p * 64 + np];
#pragma unroll
          for (int mt = 0; mt < 4; mt++) {
            f32x4 vb = acc[mt][nt];
            vb[0] += bn; vb[1] += bn; vb[2] += bn; vb[3] += bn;
            bf16x4 pk = __builtin_convertvector(vb, bf16x4);
            *(bf16x4*)(&buf[np * 136 + wm * 64 + mt * 16 + q4 * 4]) = pk;
          }
        }
      }
      __syncthreads();
#pragma unroll
      for (int i = 0; i < 2; i++) {
        int ci = tid + i * 512;
        int np = ci >> 4, c = ci & 15;
        int n = n0 + p * 64 + np;
        int h = n >> 6, hd = n & 63;
        int m = m0 + c * 8;
        int b = m >> 11, s = m & (S_ - 1);
        *(uint4*)(out + (((size_t)(b * H_ + h)) * HD_ + hd) * S_ + s) = *(const uint4*)(buf + np * 136 + c * 8);
      }
    }
  }
}

// ---------------------------------------------------------------- flash attention v4
// 512 blocks x 256 threads (4 waves). Wave owns 32 q-rows; 32x32x16 MFMA path.
// Key structural changes vs v3 (which was bound by per-step serial chain of the
// heaviest block):
//  * S^T = mfma(K, Q): score C has col = lane&31 = q  ->  softmax state (m,l,alpha)
//    is LANE-LOCAL (no __shfl broadcasts). One shfl_xor(32) merges the two row-halves.
//  * O^T = mfma(V^T, P^T): O columns = q too -> rescale/divide lane-local.
//  * P never touches LDS: v_cvt_pk_bf16_f32 + permlane32_swap build the PV B-fragments
//    in registers (T12). Removes the P write->fence->read bounce from every tile.
//  * 4-wave barrier groups, DMA staging (global_load_lds, pre-swizzled source),
//    one vmcnt(0) barrier per 64-key tile.
//  * Heavy-first LPT order: qi = t<8 ? 15-t : t-8 (ids d and d+256 complementary ->
//    uniform per-CU totals; heavy chains start at t=0). id%8 == bh%8 keeps one head's
//    K/V in one XCD L2.
// LDS 51 KB (K 16 + V 16 + epilogue transpose 18) -> all 512 blocks co-resident (2/CU).
__global__ __launch_bounds__(256, 2) void attn_kernel(
    const unsigned short* __restrict__ Q, const unsigned short* __restrict__ K,
    const unsigned short* __restrict__ Vt_g, unsigned short* __restrict__ O) {
  const int id = blockIdx.x;
  const int bh = id & 31;
  const int t = id >> 5;
  const int qi = (t < 8) ? (15 - t) : (t - 8);
  const int b = bh >> 4, h = bh & 15;
  const unsigned short* Qh = Q    + (size_t)bh * S_ * HD_;
  const unsigned short* Kh = K    + (size_t)bh * S_ * HD_;
  const unsigned short* Vh = Vt_g + (size_t)bh * HD_ * S_;   // [HD][S]

  __shared__ __align__(16) unsigned short Ks[2][64 * 64];    // [buf][key][hd^swz]  16 KB
  __shared__ __align__(16) unsigned short Vt[2][64 * 64];    // [buf][hd][key^swz]  16 KB
  __shared__ __align__(16) unsigned short Sw[4][32 * 72];    // per-wave O transpose 18 KB

  const int tid = threadIdx.x, lane = tid & 63, w = tid >> 6;
  const int myk = lane & 31, hi5 = lane >> 5;
  const int q0 = qi * 128, nkt = 2 * qi + 2;
  const int qlo = q0 + w * 32, qmax = qlo + 31;
  const int qrow = qlo + myk;

  // staging source offsets: pre-swizzled global cols, linear LDS dest (16B/thread x2)
  int kso[2], vso[2];
#pragma unroll
  for (int j = 0; j < 2; j++) {
    int c = tid + j * 256, row = c >> 3, c8 = c & 7;
    int sc_ = (c8 ^ (row & 7)) * 8;
    kso[j] = row * HD_ + sc_;
    vso[j] = row * S_ + sc_;
  }

  // Q B-frags: B[k=hi5*8+j][n=q=lane&31] per 16-wide hd slice kk
  bf16x8 qf[4];
#pragma unroll
  for (int kk = 0; kk < 4; kk++)
    qf[kk] = *(const bf16x8*)(Qh + (size_t)qrow * HD_ + kk * 16 + hi5 * 8);

  // stage tile 0
#pragma unroll
  for (int j = 0; j < 2; j++) {
    gl_lds16(Kh + kso[j], &Ks[0][0] + (tid + j * 256) * 8);
    gl_lds16(Vh + vso[j], &Vt[0][0] + (tid + j * 256) * 8);
  }

  float m_i = -1e30f, l_i = 0.f;
  f32x16 oa0, oa1;
#pragma unroll
  for (int i = 0; i < 16; i++) { oa0[i] = 0.f; oa1[i] = 0.f; }

  for (int kt = 0; kt < nkt; kt++) {
    const int k0 = kt * 64;
    bar_vm0();                                   // tile kt landed; prev-buf readers done
    if (kt + 1 < nkt) {                          // DMA next tile into other buffer
      unsigned short* Kd = &Ks[(kt + 1) & 1][0];
      unsigned short* Vd = &Vt[(kt + 1) & 1][0];
#pragma unroll
      for (int j = 0; j < 2; j++) {
        gl_lds16(Kh + (kt + 1) * 64 * HD_ + kso[j], Kd + (tid + j * 256) * 8);
        gl_lds16(Vh + (kt + 1) * 64 + vso[j],       Vd + (tid + j * 256) * 8);
      }
    }
    if (k0 > qmax) continue;                     // fully-masked tile (wave-uniform skip)

    const unsigned short* Kb = &Ks[kt & 1][0];
    const unsigned short* Vb = &Vt[kt & 1][0];

    // S^T = K.Q^T : 2 m-tiles of 32 keys, 4 hd slices. C: col=lane&31=q, 16 key-rows.
    f32x16 sc0, sc1;
#pragma unroll
    for (int i = 0; i < 16; i++) { sc0[i] = 0.f; sc1[i] = 0.f; }
    __builtin_amdgcn_s_setprio(1);
#pragma unroll
    for (int kk = 0; kk < 4; kk++) {
      const int off = ((kk * 2 + hi5) ^ (myk & 7)) * 8;
      bf16x8 a0 = *(const bf16x8*)(Kb + myk * 64 + off);
      bf16x8 a1 = *(const bf16x8*)(Kb + (32 + myk) * 64 + off);
      sc0 = __builtin_amdgcn_mfma_f32_32x32x16_bf16(a0, qf[kk], sc0, 0, 0, 0);
      sc1 = __builtin_amdgcn_mfma_f32_32x32x16_bf16(a1, qf[kk], sc1, 0, 0, 0);
    }
    __builtin_amdgcn_s_setprio(0);

    // causal mask (diagonal-overlap tiles only); key row r = (rg&3)+8*(rg>>2)+4*hi5
    if (k0 + 63 > qlo) {
#pragma unroll
      for (int rg = 0; rg < 16; rg++) {
        const int r = (rg & 3) + 8 * (rg >> 2) + 4 * hi5;
        if (k0 + r > qrow)      sc0[rg] = -1e30f;
        if (k0 + 32 + r > qrow) sc1[rg] = -1e30f;
      }
    }

    // row max: lane-local tree + one half-merge shfl
    float am[8];
#pragma unroll
    for (int i = 0; i < 8; i++)
      am[i] = fmaxf(fmaxf(sc0[i], sc0[i + 8]), fmaxf(sc1[i], sc1[i + 8]));
#pragma unroll
    for (int sr = 4; sr > 0; sr >>= 1)
#pragma unroll
      for (int i = 0; i < sr; i++) am[i] = fmaxf(am[i], am[i + sr]);
    float mx = fmaxf(am[0], __shfl_xor(am[0], 32));
    mx = fmaxf(mx, m_i);

    // T13 defer-max: rescale is fully lane-local when it fires
    if (!__all(mx - m_i <= 10.0f)) {
      float alpha = __builtin_amdgcn_exp2f(m_i - mx);
      m_i = mx;
      l_i *= alpha;
#pragma unroll
      for (int i = 0; i < 16; i++) { oa0[i] *= alpha; oa1[i] *= alpha; }
    }

    // exp2 + row sum
#pragma unroll
    for (int i = 0; i < 16; i++) sc0[i] = __builtin_amdgcn_exp2f(sc0[i] - m_i);
#pragma unroll
    for (int i = 0; i < 16; i++) sc1[i] = __builtin_amdgcn_exp2f(sc1[i] - m_i);
    float sm[8];
#pragma unroll
    for (int i = 0; i < 8; i++) sm[i] = (sc0[i] + sc0[i + 8]) + (sc1[i] + sc1[i + 8]);
#pragma unroll
    for (int sr = 4; sr > 0; sr >>= 1)
#pragma unroll
      for (int i = 0; i < sr; i++) sm[i] += sm[i + sr];
    l_i += sm[0] + __shfl_xor(sm[0], 32);

    // P -> PV B-frags IN REGISTERS (T12): pack key-pairs, permlane32_swap half-exchange.
    // word w[i] = keys {r(2i), r(2i+1)} (consecutive). Frag kk2: words
    // [swap(w0,w2).x, swap(w1,w3).x, swap(w0,w2).y, swap(w1,w3).y] (shift 4 for kk2=1).
    unsigned wa[8], wb[8];
#pragma unroll
    for (int i = 0; i < 8; i++) {
      wa[i] = cvtpk(sc0[2 * i], sc0[2 * i + 1]);
      wb[i] = cvtpk(sc1[2 * i], sc1[2 * i + 1]);
    }
    union { unsigned u[4]; bf16x8 v; } pf0, pf1, pf2, pf3;
    { u32x2 s0 = pswap(wa[0], wa[2]), s1 = pswap(wa[1], wa[3]);
      pf0.u[0] = s0[0]; pf0.u[1] = s1[0]; pf0.u[2] = s0[1]; pf0.u[3] = s1[1]; }
    { u32x2 s0 = pswap(wa[4], wa[6]), s1 = pswap(wa[5], wa[7]);
      pf1.u[0] = s0[0]; pf1.u[1] = s1[0]; pf1.u[2] = s0[1]; pf1.u[3] = s1[1]; }
    { u32x2 s0 = pswap(wb[0], wb[2]), s1 = pswap(wb[1], wb[3]);
      pf2.u[0] = s0[0]; pf2.u[1] = s1[0]; pf2.u[2] = s0[1]; pf2.u[3] = s1[1]; }
    { u32x2 s0 = pswap(wb[4], wb[6]), s1 = pswap(wb[5], wb[7]);
      pf3.u[0] = s0[0]; pf3.u[1] = s1[0]; pf3.u[2] = s0[1]; pf3.u[3] = s1[1]; }

    // O^T += V^T . P^T : A = V-frag (m=hd), B = P-frag (n=q); 4 key slots of 16
    __builtin_amdgcn_s_setprio(1);
#pragma unroll
    for (int ks = 0; ks < 4; ks++) {
      const int off = ((ks * 2 + hi5) ^ (myk & 7)) * 8;
      bf16x8 v0 = *(const bf16x8*)(Vb + myk * 64 + off);
      bf16x8 v1 = *(const bf16x8*)(Vb + (32 + myk) * 64 + off);
      bf16x8 pk = ks == 0 ? pf0.v : ks == 1 ? pf1.v : ks == 2 ? pf2.v : pf3.v;
      oa0 = __builtin_amdgcn_mfma_f32_32x32x16_bf16(v0, pk, oa0, 0, 0, 0);
      oa1 = __builtin_amdgcn_mfma_f32_32x32x16_bf16(v1, pk, oa1, 0, 0, 0);
    }
    __builtin_amdgcn_s_setprio(0);
  }

  // epilogue: lane-local 1/l, transpose O^T->O via per-wave LDS scratch, coalesced store
  const float inv = 1.0f / l_i;
#pragma unroll
  for (int i = 0; i < 16; i++) { oa0[i] *= inv; oa1[i] *= inv; }
  unsigned short* sw = &Sw[w][0];
#pragma unroll
  for (int g = 0; g < 4; g++) {                 // regs 4g..4g+3 -> hd 8g+4hi5+{0..3}
    u32x2 d0, d1;
    d0[0] = cvtpk(oa0[4 * g], oa0[4 * g + 1]);
    d0[1] = cvtpk(oa0[4 * g + 2], oa0[4 * g + 3]);
    d1[0] = cvtpk(oa1[4 * g], oa1[4 * g + 1]);
    d1[1] = cvtpk(oa1[4 * g + 2], oa1[4 * g + 3]);
    *(u32x2*)(sw + myk * 72 + g * 8 + 4 * hi5)      = d0;
    *(u32x2*)(sw + myk * 72 + 32 + g * 8 + 4 * hi5) = d1;
  }
  // wave-local RAW: compiler inserts lgkmcnt wait on the dependent reads below
#pragma unroll
  for (int rr = 0; rr < 4; rr++) {
    int qq = rr * 8 + (lane >> 3);
    uint4 d = *(const uint4*)(sw + qq * 72 + (lane & 7) * 8);
    *(uint4*)(O + ((size_t)(b * S_ + qlo + qq)) * D_ + h * 64 + (lane & 7) * 8) = d;
  }
}

// ---------------------------------------------------------------- output GEMM (unchanged)
__global__ __launch_bounds__(512) void out_gemm_kernel(
    const unsigned short* __restrict__ ab, const unsigned short* __restrict__ wot,
    const float* __restrict__ bo, float* __restrict__ out) {
  __shared__ __align__(16) unsigned short smem[6 * 4096];   // 48 KB
  const int tid = threadIdx.x;
  const int lane = tid & 63, wid = tid >> 6;
  const int wm = wid & 1, wn = wid >> 1;
  const int m0 = blockIdx.x * 128, n0 = blockIdx.y * 128;
  const int l15 = lane & 15, q4 = lane >> 4;
  const int srow = tid >> 2, skc = (tid & 3) * 8;

  f32x4 zero = {0.f, 0.f, 0.f, 0.f};
  f32x4 acc[4][2];
#pragma unroll
  for (int mt = 0; mt < 4; mt++)
#pragma unroll
    for (int nt = 0; nt < 2; nt++) acc[mt][nt] = zero;

  const unsigned short* ap = ab  + (size_t)(m0 + srow) * D_ + skc;
  const unsigned short* bp = wot + (size_t)(n0 + srow) * D_ + skc;
  gl_lds16(ap,      smem + tid * 8);
  gl_lds16(bp,      smem + 12288 + tid * 8);
  gl_lds16(ap + 32, smem + 4096 + tid * 8);
  gl_lds16(bp + 32, smem + 12288 + 4096 + tid * 8);

  int bc = 0;
  for (int it = 0; it < 32; it++) {
    if (it < 31) bar_vm2(); else bar_vm0();
    if (it + 2 < 32) {
      int bn_ = bc < 1 ? bc + 2 : bc - 1;
      gl_lds16(ap + (it + 2) * 32, smem + bn_ * 4096 + tid * 8);
      gl_lds16(bp + (it + 2) * 32, smem + 12288 + bn_ * 4096 + tid * 8);
    }
    const unsigned short* Ab = smem + bc * 4096;
    const unsigned short* Bb = smem + 12288 + bc * 4096;
    bf16x8 af[4], bfv[2];
#pragma unroll
    for (int mt = 0; mt < 4; mt++) af[mt]  = *(const bf16x8*)(Ab + (wm * 64 + mt * 16 + l15) * 32 + q4 * 8);
#pragma unroll
    for (int nt = 0; nt < 2; nt++) bfv[nt] = *(const bf16x8*)(Bb + (wn * 32 + nt * 16 + l15) * 32 + q4 * 8);
#pragma unroll
    for (int mt = 0; mt < 4; mt++)
#pragma unroll
      for (int nt = 0; nt < 2; nt++)
        acc[mt][nt] = __builtin_amdgcn_mfma_f32_16x16x32_bf16(af[mt], bfv[nt], acc[mt][nt], 0, 0, 0);
    bc = bc == 2 ? 0 : bc + 1;
  }

#pragma unroll
  for (int nt = 0; nt < 2; nt++) {
    int n = n0 + wn * 32 + nt * 16 + l15;
    float bn = bo[n];
#pragma unroll
    for (int mt = 0; mt < 4; mt++) {
#pragma unroll
      for (int r = 0; r < 4; r++) {
        int m = m0 + wm * 64 + mt * 16 + q4 * 4 + r;
        out[(size_t)m * D_ + n] = acc[mt][nt][r] + bn;
      }
    }
  }
}

// ---------------------------------------------------------------- launch
extern "C" void kernel_launch(void* const* d_in, const int* in_sizes, int n_in,
                              void* d_out, int out_size, void* d_ws, size_t ws_size,
                              hipStream_t stream) {
  const float* x  = (const float*)d_in[0];
  const float* wq = (const float*)d_in[1];
  const float* bq = (const float*)d_in[2];
  const float* wk = (const float*)d_in[3];
  const float* bk = (const float*)d_in[4];
  const float* wv = (const float*)d_in[5];
  const float* bv = (const float*)d_in[6];
  const float* wo = (const float*)d_in[7];
  const float* bo = (const float*)d_in[8];
  float* out = (float*)d_out;

  char* ws = (char*)d_ws;
  unsigned short* xb  = (unsigned short*)(ws);               // 8 MB; reused as attn out
  unsigned short* wqt = (unsigned short*)(ws + (8u  << 20));
  unsigned short* wkt = (unsigned short*)(ws + (10u << 20));
  unsigned short* wvt = (unsigned short*)(ws + (12u << 20));
  unsigned short* wot = (unsigned short*)(ws + (14u << 20));
  unsigned short* qb  = (unsigned short*)(ws + (16u << 20)); // [B,H,S,HD] bf16 (pre-scaled)
  unsigned short* kb  = (unsigned short*)(ws + (24u << 20)); // [B,H,S,HD] bf16
  unsigned short* vtg = (unsigned short*)(ws + (32u << 20)); // [B,H,HD,S] bf16 (transposed V)
  unsigned short* ab  = xb;                                  // attention output [B,S,D] bf16

  cvt_all_kernel<<<dim3(32, 32, 5), dim3(32, 8), 0, stream>>>(x, wq, wk, wv, wo, xb, wqt, wkt, wvt, wot);
  qkv_gemm_kernel<<<dim3(32, 8, 3), dim3(512), 0, stream>>>(xb, wqt, wkt, wvt, bq, bk, bv, qb, kb, vtg);
  attn_kernel<<<dim3(512), dim3(256), 0, stream>>>(qb, kb, vtg, ab);
  out_gemm_kernel<<<dim3(32, 8), dim3(512), 0, stream>>>(ab, wot, bo, out);
}